// Round 1
// baseline (343.563 us; speedup 1.0000x reference)
//
#include <hip/hip_runtime.h>
#include <math.h>

#define NN 30000
#define KK 32
#define FF 256
#define DD 128

__device__ __forceinline__ float seluf(float x) {
    const float scale = 1.0507009873554804934193349852946f;
    const float alpha = 1.6732632423543772848170429916717f;
    return x > 0.f ? scale * x : scale * alpha * expm1f(x);
}

__device__ __forceinline__ float waveReduceSum(float v) {
#pragma unroll
    for (int m = 1; m < 64; m <<= 1) v += __shfl_xor(v, m, 64);
    return v;
}

// -------- kernel 1: h0 = selu(x @ W + b) ----------------------------------
// block = 256 threads, 8 rows per block. x rows staged in LDS, W streamed
// (coalesced across the 128 col-threads, L2-resident: 128 KB).
__global__ __launch_bounds__(256) void k_linear_selu(
    const float* __restrict__ x, const float* __restrict__ W,
    const float* __restrict__ b, float* __restrict__ h0)
{
    __shared__ float xs[8 * FF];
    const int tid = threadIdx.x;
    const int blockRow = blockIdx.x * 8;
#pragma unroll
    for (int i = 0; i < 8; ++i) {
        int idx = i * 256 + tid;
        xs[idx] = x[blockRow * FF + idx];
    }
    __syncthreads();
    const int d  = tid & 127;
    const int h2 = tid >> 7;   // 0/1 -> rows {h2, h2+2, h2+4, h2+6}
    float a0 = 0.f, a1 = 0.f, a2 = 0.f, a3 = 0.f;
    for (int f = 0; f < FF; ++f) {
        float wv = W[f * DD + d];
        a0 = fmaf(xs[(h2 + 0) * FF + f], wv, a0);
        a1 = fmaf(xs[(h2 + 2) * FF + f], wv, a1);
        a2 = fmaf(xs[(h2 + 4) * FF + f], wv, a2);
        a3 = fmaf(xs[(h2 + 6) * FF + f], wv, a3);
    }
    const float bb = b[d];
    h0[(blockRow + h2 + 0) * DD + d] = seluf(a0 + bb);
    h0[(blockRow + h2 + 2) * DD + d] = seluf(a1 + bb);
    h0[(blockRow + h2 + 4) * DD + d] = seluf(a2 + bb);
    h0[(blockRow + h2 + 6) * DD + d] = seluf(a3 + bb);
}

// -------- kernel 2: h = normalize(exp_map_zero(h0)) ------------------------
// one wave per row; lane l holds elements (2l, 2l+1) as float2.
__global__ __launch_bounds__(256) void k_expmap(
    const float* __restrict__ h0, float* __restrict__ h)
{
    const int wave = threadIdx.x >> 6;
    const int lane = threadIdx.x & 63;
    const int row  = blockIdx.x * 4 + wave;
    const float2 v = *(const float2*)(h0 + row * DD + lane * 2);
    // spatial = elements 1..127 (element 0 of input ignored)
    float c = (lane ? v.x * v.x : 0.f) + v.y * v.y;
    float ldv = waveReduceSum(c);
    float nd = sqrtf(fmaxf(ldv + 1e-9f, 1e-10f));
    float t  = fminf(nd, 1.0f);
    float sc = sinhf(t) / nd;
    // normalize: time = sqrt(1 + ||space||^2), ||space||^2 = sc^2 * ldv
    float s2 = sc * sc * ldv;
    float tm = sqrtf(1.f + s2);
    float2 o;
    o.x = lane ? sc * v.x : tm;
    o.y = sc * v.y;
    *(float2*)(h + row * DD + lane * 2) = o;
}

// -------- kernel 3: msg = h @ lw  (lw = blockdiag(1, M), M 127x127) --------
__global__ __launch_bounds__(256) void k_msg(
    const float* __restrict__ h, const float* __restrict__ M,
    float* __restrict__ msg)
{
    __shared__ float hs[8 * DD];
    const int tid = threadIdx.x;
    const int blockRow = blockIdx.x * 8;
#pragma unroll
    for (int i = 0; i < 4; ++i) {
        int idx = i * 256 + tid;
        hs[idx] = h[blockRow * DD + idx];
    }
    __syncthreads();
    const int d  = tid & 127;
    const int h2 = tid >> 7;
    const int mcol = (d == 0) ? 0 : (d - 1);
    float a0 = 0.f, a1 = 0.f, a2 = 0.f, a3 = 0.f;
    for (int f = 1; f < DD; ++f) {
        float mv = M[(f - 1) * 127 + mcol];
        a0 = fmaf(hs[(h2 + 0) * DD + f], mv, a0);
        a1 = fmaf(hs[(h2 + 2) * DD + f], mv, a1);
        a2 = fmaf(hs[(h2 + 4) * DD + f], mv, a2);
        a3 = fmaf(hs[(h2 + 6) * DD + f], mv, a3);
    }
    if (d == 0) {
        msg[(blockRow + h2 + 0) * DD] = hs[(h2 + 0) * DD];
        msg[(blockRow + h2 + 2) * DD] = hs[(h2 + 2) * DD];
        msg[(blockRow + h2 + 4) * DD] = hs[(h2 + 4) * DD];
        msg[(blockRow + h2 + 6) * DD] = hs[(h2 + 6) * DD];
    } else {
        msg[(blockRow + h2 + 0) * DD + d] = a0;
        msg[(blockRow + h2 + 2) * DD + d] = a1;
        msg[(blockRow + h2 + 4) * DD + d] = a2;
        msg[(blockRow + h2 + 6) * DD + d] = a3;
    }
}

// -------- kernel 4: gather + hyperbolic mean + activation + normalize ------
// one wave per node; lane l holds components (2l, 2l+1); all reductions
// in-wave (no LDS, no barriers).
__global__ __launch_bounds__(256) void k_layer(
    const float* __restrict__ msg, const int* __restrict__ adj,
    const float* __restrict__ w, float* __restrict__ out)
{
    const int wave = threadIdx.x >> 6;
    const int lane = threadIdx.x & 63;
    const int node = blockIdx.x * 4 + wave;

    const int   av = adj[node * KK + (lane & 31)];
    const float wv = w[node * KK + (lane & 31)];

    float km0 = 0.f, km1 = 0.f, lamsum = 0.f;
#pragma unroll 4
    for (int j = 0; j < KK; ++j) {
        const int   idx = __shfl(av, j, 64);
        const float wj  = __shfl(wv, j, 64);
        const float2 v  = *(const float2*)(msg + (size_t)idx * DD + lane * 2);
        const float nbr0 = __shfl(v.x, 0, 64);
        const float rn = 1.0f / nbr0;
        const float k0 = v.x * rn;
        const float k1 = v.y * rn;
        float c = (lane ? k0 * k0 : 0.f) + k1 * k1;
        float kn = waveReduceSum(c);
        kn = fminf(fmaxf(kn, 0.f), 0.9f);
        const float lam = wj / sqrtf(1.f - kn);
        if (lane) km0 = fmaf(lam, k0, km0);
        km1 = fmaf(lam, k1, km1);
        lamsum += lam;
    }
    const float rl = 1.f / lamsum;
    const float m0 = km0 * rl;
    const float m1 = km1 * rl;
    float c2 = (lane ? m0 * m0 : 0.f) + m1 * m1;
    const float kn2 = fminf(waveReduceSum(c2), 0.9f);
    const float invs = 1.f / sqrtf(1.f - kn2);   // h[0]
    // lorentz activation: p = h[1:]/(h[0]+1), selu
    const float pd = invs + 1.f;
    const float p0 = lane ? seluf(m0 * invs / pd) : 0.f;
    const float p1 = seluf(m1 * invs / pd);
    float pc = p0 * p0 + p1 * p1;
    const float pn = waveReduceSum(pc);
    const float dn = 1.f - pn + 1e-6f;
    const float rdn = 1.f / dn;
    const float sp0 = 2.f * p0 * rdn;
    const float sp1 = 2.f * p1 * rdn;
    // normalize: time = sqrt(1 + sum sp^2) = sqrt(1 + 4*pn/dn^2)
    const float tm = sqrtf(1.f + 4.f * pn * rdn * rdn);
    float2 o;
    o.x = lane ? sp0 : tm;
    o.y = sp1;
    *(float2*)(out + (size_t)node * DD + lane * 2) = o;
}

extern "C" void kernel_launch(void* const* d_in, const int* in_sizes, int n_in,
                              void* d_out, int out_size, void* d_ws, size_t ws_size,
                              hipStream_t stream) {
    const float* x     = (const float*)d_in[0];
    const int*   adj   = (const int*)d_in[1];
    const float* w     = (const float*)d_in[2];
    const float* lin_W = (const float*)d_in[3];
    const float* lin_b = (const float*)d_in[4];
    const float* M     = (const float*)d_in[5];
    float* h   = (float*)d_out;            // N*D, ping
    float* tmp = (float*)d_ws;             // N*D, pong (h0 / msg)

    // h0 = selu(x@W+b) -> tmp ; h = normalize(expmap(tmp))
    k_linear_selu<<<NN / 8, 256, 0, stream>>>(x, lin_W, lin_b, tmp);
    k_expmap<<<NN / 4, 256, 0, stream>>>(tmp, h);
    // layer 0
    k_msg<<<NN / 8, 256, 0, stream>>>(h, M, tmp);
    k_layer<<<NN / 4, 256, 0, stream>>>(tmp, adj, w, h);
    // layer 1
    k_msg<<<NN / 8, 256, 0, stream>>>(h, M, tmp);
    k_layer<<<NN / 4, 256, 0, stream>>>(tmp, adj, w, h);
}

// Round 2
// 272.947 us; speedup vs baseline: 1.2587x; 1.2587x over previous
//
#include <hip/hip_runtime.h>
#include <math.h>

#define NN 30000
#define KK 32
#define FF 256
#define DD 128

__device__ __forceinline__ float seluf(float x) {
    const float scale = 1.0507009873554804934193349852946f;
    const float alpha = 1.6732632423543772848170429916717f;
    return x > 0.f ? scale * x : scale * alpha * expm1f(x);
}

__device__ __forceinline__ float waveReduceSum(float v) {
#pragma unroll
    for (int m = 1; m < 64; m <<= 1) v += __shfl_xor(v, m, 64);
    return v;
}

// -------- kernel 1: h0 = selu(x @ W + b) ----------------------------------
__global__ __launch_bounds__(256) void k_linear_selu(
    const float* __restrict__ x, const float* __restrict__ W,
    const float* __restrict__ b, float* __restrict__ h0)
{
    __shared__ float xs[8 * FF];
    const int tid = threadIdx.x;
    const int blockRow = blockIdx.x * 8;
#pragma unroll
    for (int i = 0; i < 8; ++i) {
        int idx = i * 256 + tid;
        xs[idx] = x[blockRow * FF + idx];
    }
    __syncthreads();
    const int d  = tid & 127;
    const int h2 = tid >> 7;
    float a0 = 0.f, a1 = 0.f, a2 = 0.f, a3 = 0.f;
    for (int f = 0; f < FF; ++f) {
        float wv = W[f * DD + d];
        a0 = fmaf(xs[(h2 + 0) * FF + f], wv, a0);
        a1 = fmaf(xs[(h2 + 2) * FF + f], wv, a1);
        a2 = fmaf(xs[(h2 + 4) * FF + f], wv, a2);
        a3 = fmaf(xs[(h2 + 6) * FF + f], wv, a3);
    }
    const float bb = b[d];
    h0[(blockRow + h2 + 0) * DD + d] = seluf(a0 + bb);
    h0[(blockRow + h2 + 2) * DD + d] = seluf(a1 + bb);
    h0[(blockRow + h2 + 4) * DD + d] = seluf(a2 + bb);
    h0[(blockRow + h2 + 6) * DD + d] = seluf(a3 + bb);
}

// -------- kernel 2: h = normalize(exp_map_zero(h0)) ------------------------
__global__ __launch_bounds__(256) void k_expmap(
    const float* __restrict__ h0, float* __restrict__ h)
{
    const int wave = threadIdx.x >> 6;
    const int lane = threadIdx.x & 63;
    const int row  = blockIdx.x * 4 + wave;
    const float2 v = *(const float2*)(h0 + row * DD + lane * 2);
    float c = (lane ? v.x * v.x : 0.f) + v.y * v.y;
    float ldv = waveReduceSum(c);
    float nd = sqrtf(fmaxf(ldv + 1e-9f, 1e-10f));
    float t  = fminf(nd, 1.0f);
    float sc = sinhf(t) / nd;
    float s2 = sc * sc * ldv;
    float tm = sqrtf(1.f + s2);
    float2 o;
    o.x = lane ? sc * v.x : tm;
    o.y = sc * v.y;
    *(float2*)(h + row * DD + lane * 2) = o;
}

// -------- kernel 3: msg = h @ lw  (lw = blockdiag(1, M), M 127x127) --------
__global__ __launch_bounds__(256) void k_msg(
    const float* __restrict__ h, const float* __restrict__ M,
    float* __restrict__ msg)
{
    __shared__ float hs[8 * DD];
    const int tid = threadIdx.x;
    const int blockRow = blockIdx.x * 8;
#pragma unroll
    for (int i = 0; i < 4; ++i) {
        int idx = i * 256 + tid;
        hs[idx] = h[blockRow * DD + idx];
    }
    __syncthreads();
    const int d  = tid & 127;
    const int h2 = tid >> 7;
    const int mcol = (d == 0) ? 0 : (d - 1);
    float a0 = 0.f, a1 = 0.f, a2 = 0.f, a3 = 0.f;
    for (int f = 1; f < DD; ++f) {
        float mv = M[(f - 1) * 127 + mcol];
        a0 = fmaf(hs[(h2 + 0) * DD + f], mv, a0);
        a1 = fmaf(hs[(h2 + 2) * DD + f], mv, a1);
        a2 = fmaf(hs[(h2 + 4) * DD + f], mv, a2);
        a3 = fmaf(hs[(h2 + 6) * DD + f], mv, a3);
    }
    if (d == 0) {
        msg[(blockRow + h2 + 0) * DD] = hs[(h2 + 0) * DD];
        msg[(blockRow + h2 + 2) * DD] = hs[(h2 + 2) * DD];
        msg[(blockRow + h2 + 4) * DD] = hs[(h2 + 4) * DD];
        msg[(blockRow + h2 + 6) * DD] = hs[(h2 + 6) * DD];
    } else {
        msg[(blockRow + h2 + 0) * DD + d] = a0;
        msg[(blockRow + h2 + 2) * DD + d] = a1;
        msg[(blockRow + h2 + 4) * DD + d] = a2;
        msg[(blockRow + h2 + 6) * DD + d] = a3;
    }
}

// -------- kernel 3b: in-place per-row precompute ---------------------------
// msg'[d] = msg[d]/msg[0] (the Klein coords k_d), and msg'[0] = f =
// 1/sqrt(1 - clip(sum k^2, 0, 0.9)). One wave per row.
__global__ __launch_bounds__(256) void k_aux(float* __restrict__ msg)
{
    const int wave = threadIdx.x >> 6;
    const int lane = threadIdx.x & 63;
    const int row  = blockIdx.x * 4 + wave;
    float2 v = *(const float2*)(msg + (size_t)row * DD + lane * 2);
    const float t0 = __shfl(v.x, 0, 64);   // msg[row][0] (>= 1)
    const float rn = 1.f / t0;
    v.x *= rn;
    v.y *= rn;
    float c = (lane ? v.x * v.x : 0.f) + v.y * v.y;
    float kn = waveReduceSum(c);
    kn = fminf(fmaxf(kn, 0.f), 0.9f);
    const float f = 1.f / sqrtf(1.f - kn);
    if (lane == 0) v.x = f;
    *(float2*)(msg + (size_t)row * DD + lane * 2) = v;
}

// -------- kernel 4: gather + weighted mean + activation + normalize --------
// one wave per node; per-neighbor work is now 2 shfl + 2 fma + 1 load.
__global__ __launch_bounds__(256) void k_layer(
    const float* __restrict__ msg, const int* __restrict__ adj,
    const float* __restrict__ w, float* __restrict__ out)
{
    const int wave = threadIdx.x >> 6;
    const int lane = threadIdx.x & 63;
    const int node = blockIdx.x * 4 + wave;

    const int   av = adj[node * KK + (lane & 31)];
    const float wv = w[node * KK + (lane & 31)];
    const float f  = msg[(size_t)av * DD];    // per-row factor (header slot)
    const float lam = wv * f;                 // = w / sqrt(1-kn)
    // lamsum over the 32-lane group (both halves hold identical data)
    float ls = lam;
#pragma unroll
    for (int m = 1; m < 32; m <<= 1) ls += __shfl_xor(ls, m, 64);

    float km0 = 0.f, km1 = 0.f;
#pragma unroll 8
    for (int j = 0; j < KK; ++j) {
        const int   idx = __shfl(av, j, 64);
        const float cj  = __shfl(lam, j, 64);
        const float2 v  = *(const float2*)(msg + (size_t)idx * DD + lane * 2);
        km0 = fmaf(cj, v.x, km0);   // lane0 garbage, masked below
        km1 = fmaf(cj, v.y, km1);
    }
    const float rl = 1.f / ls;
    const float m0 = km0 * rl;
    const float m1 = km1 * rl;
    float c2 = (lane ? m0 * m0 : 0.f) + m1 * m1;
    const float kn2 = fminf(waveReduceSum(c2), 0.9f);
    const float invs = 1.f / sqrtf(1.f - kn2);   // h[0]
    const float pd = invs + 1.f;
    const float p0 = lane ? seluf(m0 * invs / pd) : 0.f;
    const float p1 = seluf(m1 * invs / pd);
    float pc = p0 * p0 + p1 * p1;
    const float pn = waveReduceSum(pc);
    const float rdn = 1.f / (1.f - pn + 1e-6f);
    const float tm = sqrtf(1.f + 4.f * pn * rdn * rdn);
    float2 o;
    o.x = lane ? 2.f * p0 * rdn : tm;
    o.y = 2.f * p1 * rdn;
    *(float2*)(out + (size_t)node * DD + lane * 2) = o;
}

extern "C" void kernel_launch(void* const* d_in, const int* in_sizes, int n_in,
                              void* d_out, int out_size, void* d_ws, size_t ws_size,
                              hipStream_t stream) {
    const float* x     = (const float*)d_in[0];
    const int*   adj   = (const int*)d_in[1];
    const float* w     = (const float*)d_in[2];
    const float* lin_W = (const float*)d_in[3];
    const float* lin_b = (const float*)d_in[4];
    const float* M     = (const float*)d_in[5];
    float* h   = (float*)d_out;            // N*D, ping
    float* tmp = (float*)d_ws;             // N*D, pong (h0 / msg)

    k_linear_selu<<<NN / 8, 256, 0, stream>>>(x, lin_W, lin_b, tmp);
    k_expmap<<<NN / 4, 256, 0, stream>>>(tmp, h);
    // layer 0
    k_msg<<<NN / 8, 256, 0, stream>>>(h, M, tmp);
    k_aux<<<NN / 4, 256, 0, stream>>>(tmp);
    k_layer<<<NN / 4, 256, 0, stream>>>(tmp, adj, w, h);
    // layer 1
    k_msg<<<NN / 8, 256, 0, stream>>>(h, M, tmp);
    k_aux<<<NN / 4, 256, 0, stream>>>(tmp);
    k_layer<<<NN / 4, 256, 0, stream>>>(tmp, adj, w, h);
}

// Round 3
// 208.136 us; speedup vs baseline: 1.6507x; 1.3114x over previous
//
#include <hip/hip_runtime.h>
#include <hip/hip_fp16.h>
#include <math.h>

#define NN 30000
#define KK 32
#define FF 256
#define DD 128

__device__ __forceinline__ float seluf(float x) {
    const float scale = 1.0507009873554804934193349852946f;
    const float alpha = 1.6732632423543772848170429916717f;
    return x > 0.f ? scale * x : scale * alpha * expm1f(x);
}

__device__ __forceinline__ float waveReduceSum(float v) {
#pragma unroll
    for (int m = 1; m < 64; m <<= 1) v += __shfl_xor(v, m, 64);
    return v;
}

__device__ __forceinline__ void waveReduce4(float& a, float& b, float& c, float& d) {
#pragma unroll
    for (int m = 1; m < 64; m <<= 1) {
        a += __shfl_xor(a, m, 64);
        b += __shfl_xor(b, m, 64);
        c += __shfl_xor(c, m, 64);
        d += __shfl_xor(d, m, 64);
    }
}

// -------- kernel 1: h = normalize(exp_map_zero(selu(x @ W + b))) -----------
// block = 256 threads, 8 rows. Row r's 128 cols live on threads h2*128+d
// (2 waves); expmap reduction via in-wave butterfly + 4x4 LDS exchange.
__global__ __launch_bounds__(256) void k_lin_exp(
    const float* __restrict__ x, const float* __restrict__ W,
    const float* __restrict__ b, float* __restrict__ h)
{
    __shared__ float xs[8 * FF];
    __shared__ float red[4][4];
    const int tid = threadIdx.x;
    const int blockRow = blockIdx.x * 8;
#pragma unroll
    for (int i = 0; i < 8; ++i) {
        int idx = i * 256 + tid;
        xs[idx] = x[blockRow * FF + idx];
    }
    __syncthreads();
    const int d  = tid & 127;
    const int h2 = tid >> 7;
    float a0 = 0.f, a1 = 0.f, a2 = 0.f, a3 = 0.f;
    for (int f = 0; f < FF; ++f) {
        float wv = W[f * DD + d];
        a0 = fmaf(xs[(h2 + 0) * FF + f], wv, a0);
        a1 = fmaf(xs[(h2 + 2) * FF + f], wv, a1);
        a2 = fmaf(xs[(h2 + 4) * FF + f], wv, a2);
        a3 = fmaf(xs[(h2 + 6) * FF + f], wv, a3);
    }
    const float bb = b[d];
    a0 = seluf(a0 + bb); a1 = seluf(a1 + bb);
    a2 = seluf(a2 + bb); a3 = seluf(a3 + bb);
    // spatial norm per row (exclude d==0)
    float c0 = d ? a0 * a0 : 0.f, c1 = d ? a1 * a1 : 0.f;
    float c2 = d ? a2 * a2 : 0.f, c3 = d ? a3 * a3 : 0.f;
    waveReduce4(c0, c1, c2, c3);
    const int wv_ = tid >> 6;
    if ((tid & 63) == 0) { red[wv_][0] = c0; red[wv_][1] = c1; red[wv_][2] = c2; red[wv_][3] = c3; }
    __syncthreads();
    const float acc[4] = {a0, a1, a2, a3};
#pragma unroll
    for (int i = 0; i < 4; ++i) {
        const float ldv = red[2 * h2][i] + red[2 * h2 + 1][i];
        const float nd = sqrtf(fmaxf(ldv + 1e-9f, 1e-10f));
        const float t  = fminf(nd, 1.0f);
        const float sc = sinhf(t) / nd;
        const float tm = sqrtf(1.f + sc * sc * ldv);
        h[(blockRow + h2 + 2 * i) * DD + d] = d ? sc * acc[i] : tm;
    }
}

// -------- kernel 2: fp16 gather table = aux(h @ blockdiag(1,M)) ------------
// table[row][0] = f = 1/sqrt(1-clip(kn)), table[row][d>=1] = Klein coord k_d.
__global__ __launch_bounds__(256) void k_msg_aux(
    const float* __restrict__ h, const float* __restrict__ M,
    __half* __restrict__ table)
{
    __shared__ float hs[8 * DD];
    __shared__ float red[4][4];
    const int tid = threadIdx.x;
    const int blockRow = blockIdx.x * 8;
#pragma unroll
    for (int i = 0; i < 4; ++i) {
        int idx = i * 256 + tid;
        hs[idx] = h[blockRow * DD + idx];
    }
    __syncthreads();
    const int d  = tid & 127;
    const int h2 = tid >> 7;
    const int mcol = d ? (d - 1) : 0;
    float a0 = 0.f, a1 = 0.f, a2 = 0.f, a3 = 0.f;
    for (int f = 1; f < DD; ++f) {
        float mv = M[(f - 1) * 127 + mcol];
        a0 = fmaf(hs[(h2 + 0) * DD + f], mv, a0);
        a1 = fmaf(hs[(h2 + 2) * DD + f], mv, a1);
        a2 = fmaf(hs[(h2 + 4) * DD + f], mv, a2);
        a3 = fmaf(hs[(h2 + 6) * DD + f], mv, a3);
    }
    // Klein coords: k = spatial / time  (time passthrough since lw[0][0]=1)
    a0 *= 1.f / hs[(h2 + 0) * DD];
    a1 *= 1.f / hs[(h2 + 2) * DD];
    a2 *= 1.f / hs[(h2 + 4) * DD];
    a3 *= 1.f / hs[(h2 + 6) * DD];
    float c0 = d ? a0 * a0 : 0.f, c1 = d ? a1 * a1 : 0.f;
    float c2 = d ? a2 * a2 : 0.f, c3 = d ? a3 * a3 : 0.f;
    waveReduce4(c0, c1, c2, c3);
    const int wv_ = tid >> 6;
    if ((tid & 63) == 0) { red[wv_][0] = c0; red[wv_][1] = c1; red[wv_][2] = c2; red[wv_][3] = c3; }
    __syncthreads();
    const float acc[4] = {a0, a1, a2, a3};
#pragma unroll
    for (int i = 0; i < 4; ++i) {
        float kn = red[2 * h2][i] + red[2 * h2 + 1][i];
        kn = fminf(fmaxf(kn, 0.f), 0.9f);
        const float f = 1.f / sqrtf(1.f - kn);
        table[(size_t)(blockRow + h2 + 2 * i) * DD + d] = __float2half(d ? acc[i] : f);
    }
}

// -------- kernel 3: gather + weighted mean + activation + normalize --------
// one wave per node; fp16 table rows are 256 B (64 lanes x half2).
__global__ __launch_bounds__(256) void k_layer(
    const __half* __restrict__ table, const int* __restrict__ adj,
    const float* __restrict__ w, float* __restrict__ out)
{
    const int wave = threadIdx.x >> 6;
    const int lane = threadIdx.x & 63;
    const int node = blockIdx.x * 4 + wave;

    const int   av = adj[node * KK + (lane & 31)];
    const float wv = w[node * KK + (lane & 31)];
    const float f  = __half2float(table[(size_t)av * DD]);
    const float lam = wv * f;
    float ls = lam;
#pragma unroll
    for (int m = 1; m < 32; m <<= 1) ls += __shfl_xor(ls, m, 64);

    float km0 = 0.f, km1 = 0.f;
#pragma unroll 8
    for (int j = 0; j < KK; ++j) {
        const int   idx = __shfl(av, j, 64);
        const float cj  = __shfl(lam, j, 64);
        const __half2 hh = *(const __half2*)(table + (size_t)idx * DD + lane * 2);
        const float2 v = __half22float2(hh);
        km0 = fmaf(cj, v.x, km0);   // lane0.x holds f-header, masked below
        km1 = fmaf(cj, v.y, km1);
    }
    const float rl = 1.f / ls;
    const float m0 = km0 * rl;
    const float m1 = km1 * rl;
    float c2 = (lane ? m0 * m0 : 0.f) + m1 * m1;
    const float kn2 = fminf(waveReduceSum(c2), 0.9f);
    const float invs = 1.f / sqrtf(1.f - kn2);   // h[0]
    const float pd = invs + 1.f;
    const float p0 = lane ? seluf(m0 * invs / pd) : 0.f;
    const float p1 = seluf(m1 * invs / pd);
    float pc = p0 * p0 + p1 * p1;
    const float pn = waveReduceSum(pc);
    const float rdn = 1.f / (1.f - pn + 1e-6f);
    const float tm = sqrtf(1.f + 4.f * pn * rdn * rdn);
    float2 o;
    o.x = lane ? 2.f * p0 * rdn : tm;
    o.y = 2.f * p1 * rdn;
    *(float2*)(out + (size_t)node * DD + lane * 2) = o;
}

extern "C" void kernel_launch(void* const* d_in, const int* in_sizes, int n_in,
                              void* d_out, int out_size, void* d_ws, size_t ws_size,
                              hipStream_t stream) {
    const float* x     = (const float*)d_in[0];
    const int*   adj   = (const int*)d_in[1];
    const float* w     = (const float*)d_in[2];
    const float* lin_W = (const float*)d_in[3];
    const float* lin_b = (const float*)d_in[4];
    const float* M     = (const float*)d_in[5];
    float*  h     = (float*)d_out;        // N*D fp32, ping
    __half* table = (__half*)d_ws;        // N*D fp16 gather table (7.7 MB)

    k_lin_exp<<<NN / 8, 256, 0, stream>>>(x, lin_W, lin_b, h);
    // layer 0
    k_msg_aux<<<NN / 8, 256, 0, stream>>>(h, M, table);
    k_layer<<<NN / 4, 256, 0, stream>>>(table, adj, w, h);
    // layer 1
    k_msg_aux<<<NN / 8, 256, 0, stream>>>(h, M, table);
    k_layer<<<NN / 4, 256, 0, stream>>>(table, adj, w, h);
}

// Round 4
// 160.876 us; speedup vs baseline: 2.1356x; 1.2938x over previous
//
#include <hip/hip_runtime.h>
#include <hip/hip_fp16.h>
#include <math.h>

#define NN 30000
#define KK 32
#define FF 256
#define DD 128

__device__ __forceinline__ float seluf(float x) {
    const float scale = 1.0507009873554804934193349852946f;
    const float alpha = 1.6732632423543772848170429916717f;
    return x > 0.f ? scale * x : scale * alpha * expm1f(x);
}

__device__ __forceinline__ float waveReduceSum(float v) {
#pragma unroll
    for (int m = 1; m < 64; m <<= 1) v += __shfl_xor(v, m, 64);
    return v;
}

// reduce across the 32 lanes of a half-wave (xor masks < 32 never cross halves)
__device__ __forceinline__ float halfReduceSum(float v) {
#pragma unroll
    for (int m = 1; m < 32; m <<= 1) v += __shfl_xor(v, m, 64);
    return v;
}

// -------- kernel 1: h = normalize(exp_map_zero(selu(x @ W + b))) -----------
// 24 rows/block, 256 threads. Thread (cc=t&31, rg=t>>5) owns rows
// {rg, rg+8, rg+16} x cols {4cc..4cc+3} (12 accumulators). W staged in LDS
// per 16-f slab; x rows staged once. LDS per 48 FMAs: 3 broadcast b128 +
// 4 full b128 -> FMA-issue-bound.
__global__ __launch_bounds__(256) void k_lin_exp(
    const float* __restrict__ x, const float* __restrict__ W,
    const float* __restrict__ b, float* __restrict__ h)
{
    __shared__ __align__(16) float xs[24 * FF];   // 24 KB
    __shared__ __align__(16) float wl[16 * DD];   // 8 KB
    const int tid = threadIdx.x;
    const int blockRow = blockIdx.x * 24;

    const float4* xg = (const float4*)(x + (size_t)blockRow * FF);
#pragma unroll
    for (int i = 0; i < 6; ++i)
        ((float4*)xs)[i * 256 + tid] = xg[i * 256 + tid];

    const int cc = tid & 31;
    const int rg = tid >> 5;
    const float4 bias = *(const float4*)(b + 4 * cc);
    float4 acc[3];
    acc[0] = acc[1] = acc[2] = float4{0.f, 0.f, 0.f, 0.f};

    for (int s = 0; s < 16; ++s) {
        const int f0 = s * 16;
        __syncthreads();   // protect wl from previous slab's readers (also covers xs on s=0)
        const float4* wg = (const float4*)(W + (size_t)f0 * DD);
#pragma unroll
        for (int i = 0; i < 2; ++i)
            ((float4*)wl)[i * 256 + tid] = wg[i * 256 + tid];
        __syncthreads();
#pragma unroll
        for (int q = 0; q < 4; ++q) {
            const float4 wv0 = *(const float4*)&wl[(q * 4 + 0) * DD + 4 * cc];
            const float4 wv1 = *(const float4*)&wl[(q * 4 + 1) * DD + 4 * cc];
            const float4 wv2 = *(const float4*)&wl[(q * 4 + 2) * DD + 4 * cc];
            const float4 wv3 = *(const float4*)&wl[(q * 4 + 3) * DD + 4 * cc];
#pragma unroll
            for (int r = 0; r < 3; ++r) {
                const float4 xv = *(const float4*)&xs[(rg + 8 * r) * FF + f0 + q * 4];
                acc[r].x = fmaf(xv.x, wv0.x, acc[r].x);
                acc[r].y = fmaf(xv.x, wv0.y, acc[r].y);
                acc[r].z = fmaf(xv.x, wv0.z, acc[r].z);
                acc[r].w = fmaf(xv.x, wv0.w, acc[r].w);
                acc[r].x = fmaf(xv.y, wv1.x, acc[r].x);
                acc[r].y = fmaf(xv.y, wv1.y, acc[r].y);
                acc[r].z = fmaf(xv.y, wv1.z, acc[r].z);
                acc[r].w = fmaf(xv.y, wv1.w, acc[r].w);
                acc[r].x = fmaf(xv.z, wv2.x, acc[r].x);
                acc[r].y = fmaf(xv.z, wv2.y, acc[r].y);
                acc[r].z = fmaf(xv.z, wv2.z, acc[r].z);
                acc[r].w = fmaf(xv.z, wv2.w, acc[r].w);
                acc[r].x = fmaf(xv.w, wv3.x, acc[r].x);
                acc[r].y = fmaf(xv.w, wv3.y, acc[r].y);
                acc[r].z = fmaf(xv.w, wv3.z, acc[r].z);
                acc[r].w = fmaf(xv.w, wv3.w, acc[r].w);
            }
        }
    }

#pragma unroll
    for (int r = 0; r < 3; ++r) {
        const int row = blockRow + rg + 8 * r;
        float4 v;
        v.x = seluf(acc[r].x + bias.x);
        v.y = seluf(acc[r].y + bias.y);
        v.z = seluf(acc[r].z + bias.z);
        v.w = seluf(acc[r].w + bias.w);
        float part = (cc ? v.x * v.x : 0.f) + v.y * v.y + v.z * v.z + v.w * v.w;
        const float ldv = halfReduceSum(part);
        const float nd = sqrtf(fmaxf(ldv + 1e-9f, 1e-10f));
        const float t  = fminf(nd, 1.0f);
        const float sc = sinhf(t) / nd;
        const float tm = sqrtf(1.f + sc * sc * ldv);
        float4 o;
        o.x = cc ? sc * v.x : tm;
        o.y = sc * v.y;
        o.z = sc * v.z;
        o.w = sc * v.w;
        *(float4*)(h + (size_t)row * DD + 4 * cc) = o;
    }
}

// -------- kernel 2: fp16 gather table = aux(h @ blockdiag(1,M)) ------------
// Same tiling. M' is the shifted/padded matrix: M'[f][c'] = (f>=1 && c'<127)
// ? M[f-1][c'] : 0, so all LDS reads stay b128-aligned and the f=0 / col-127
// contributions vanish. table[row][0]=f-header, [d>=1]=Klein coord.
__global__ __launch_bounds__(256) void k_msg_aux(
    const float* __restrict__ h, const float* __restrict__ M,
    __half* __restrict__ table)
{
    __shared__ __align__(16) float xs[24 * DD];   // 12 KB
    __shared__ __align__(16) float ml[16 * DD];   // 8 KB
    __shared__ float ht[24];
    const int tid = threadIdx.x;
    const int blockRow = blockIdx.x * 24;

    const float4* hg = (const float4*)(h + (size_t)blockRow * DD);
#pragma unroll
    for (int i = 0; i < 3; ++i) {
        const int idx = i * 256 + tid;
        const float4 v = hg[idx];
        ((float4*)xs)[idx] = v;
        if ((idx & 31) == 0) ht[idx >> 5] = v.x;   // time coord of each row
    }

    const int cc = tid & 31;
    const int rg = tid >> 5;
    float4 acc[3];
    acc[0] = acc[1] = acc[2] = float4{0.f, 0.f, 0.f, 0.f};

    for (int s = 0; s < 8; ++s) {
        const int f0 = s * 16;
        __syncthreads();
#pragma unroll
        for (int i = 0; i < 8; ++i) {
            const int idx = i * 256 + tid;
            const int fs = idx >> 7, c = idx & 127;
            const int f = f0 + fs;
            ml[idx] = (f >= 1 && c < 127) ? M[(f - 1) * 127 + c] : 0.f;
        }
        __syncthreads();
#pragma unroll
        for (int q = 0; q < 4; ++q) {
            const float4 wv0 = *(const float4*)&ml[(q * 4 + 0) * DD + 4 * cc];
            const float4 wv1 = *(const float4*)&ml[(q * 4 + 1) * DD + 4 * cc];
            const float4 wv2 = *(const float4*)&ml[(q * 4 + 2) * DD + 4 * cc];
            const float4 wv3 = *(const float4*)&ml[(q * 4 + 3) * DD + 4 * cc];
#pragma unroll
            for (int r = 0; r < 3; ++r) {
                const float4 xv = *(const float4*)&xs[(rg + 8 * r) * DD + f0 + q * 4];
                acc[r].x = fmaf(xv.x, wv0.x, acc[r].x);
                acc[r].y = fmaf(xv.x, wv0.y, acc[r].y);
                acc[r].z = fmaf(xv.x, wv0.z, acc[r].z);
                acc[r].w = fmaf(xv.x, wv0.w, acc[r].w);
                acc[r].x = fmaf(xv.y, wv1.x, acc[r].x);
                acc[r].y = fmaf(xv.y, wv1.y, acc[r].y);
                acc[r].z = fmaf(xv.y, wv1.z, acc[r].z);
                acc[r].w = fmaf(xv.y, wv1.w, acc[r].w);
                acc[r].x = fmaf(xv.z, wv2.x, acc[r].x);
                acc[r].y = fmaf(xv.z, wv2.y, acc[r].y);
                acc[r].z = fmaf(xv.z, wv2.z, acc[r].z);
                acc[r].w = fmaf(xv.z, wv2.w, acc[r].w);
                acc[r].x = fmaf(xv.w, wv3.x, acc[r].x);
                acc[r].y = fmaf(xv.w, wv3.y, acc[r].y);
                acc[r].z = fmaf(xv.w, wv3.z, acc[r].z);
                acc[r].w = fmaf(xv.w, wv3.w, acc[r].w);
            }
        }
    }

#pragma unroll
    for (int r = 0; r < 3; ++r) {
        const int lrow = rg + 8 * r;
        const int row = blockRow + lrow;
        const float rn = 1.f / ht[lrow];
        float4 k4;
        k4.x = acc[r].x * rn;
        k4.y = acc[r].y * rn;
        k4.z = acc[r].z * rn;
        k4.w = acc[r].w * rn;   // cc==31 -> col 127 pad, acc 0
        float part = k4.x * k4.x + k4.y * k4.y + k4.z * k4.z + k4.w * k4.w;
        float kn = halfReduceSum(part);
        kn = fminf(fmaxf(kn, 0.f), 0.9f);
        const float fh = 1.f / sqrtf(1.f - kn);
        __half* trow = table + (size_t)row * DD;
        const int d0 = 1 + 4 * cc;
        trow[d0]     = __float2half(k4.x);
        trow[d0 + 1] = __float2half(k4.y);
        trow[d0 + 2] = __float2half(k4.z);
        if (cc < 31) trow[d0 + 3] = __float2half(k4.w);
        if (cc == 0) trow[0] = __float2half(fh);
    }
}

// -------- kernel 3: gather + weighted mean + activation + normalize --------
__global__ __launch_bounds__(256) void k_layer(
    const __half* __restrict__ table, const int* __restrict__ adj,
    const float* __restrict__ w, float* __restrict__ out)
{
    const int wave = threadIdx.x >> 6;
    const int lane = threadIdx.x & 63;
    const int node = blockIdx.x * 4 + wave;

    const int   av = adj[node * KK + (lane & 31)];
    const float wv = w[node * KK + (lane & 31)];
    const float f  = __half2float(table[(size_t)av * DD]);
    const float lam = wv * f;
    float ls = lam;
#pragma unroll
    for (int m = 1; m < 32; m <<= 1) ls += __shfl_xor(ls, m, 64);

    float km0 = 0.f, km1 = 0.f;
#pragma unroll 8
    for (int j = 0; j < KK; ++j) {
        const int   idx = __shfl(av, j, 64);
        const float cj  = __shfl(lam, j, 64);
        const __half2 hh = *(const __half2*)(table + (size_t)idx * DD + lane * 2);
        const float2 v = __half22float2(hh);
        km0 = fmaf(cj, v.x, km0);   // lane0.x holds f-header, masked below
        km1 = fmaf(cj, v.y, km1);
    }
    const float rl = 1.f / ls;
    const float m0 = km0 * rl;
    const float m1 = km1 * rl;
    float c2 = (lane ? m0 * m0 : 0.f) + m1 * m1;
    const float kn2 = fminf(waveReduceSum(c2), 0.9f);
    const float invs = 1.f / sqrtf(1.f - kn2);
    const float pd = invs + 1.f;
    const float p0 = lane ? seluf(m0 * invs / pd) : 0.f;
    const float p1 = seluf(m1 * invs / pd);
    float pc = p0 * p0 + p1 * p1;
    const float pn = waveReduceSum(pc);
    const float rdn = 1.f / (1.f - pn + 1e-6f);
    const float tm = sqrtf(1.f + 4.f * pn * rdn * rdn);
    float2 o;
    o.x = lane ? 2.f * p0 * rdn : tm;
    o.y = 2.f * p1 * rdn;
    *(float2*)(out + (size_t)node * DD + lane * 2) = o;
}

extern "C" void kernel_launch(void* const* d_in, const int* in_sizes, int n_in,
                              void* d_out, int out_size, void* d_ws, size_t ws_size,
                              hipStream_t stream) {
    const float* x     = (const float*)d_in[0];
    const int*   adj   = (const int*)d_in[1];
    const float* w     = (const float*)d_in[2];
    const float* lin_W = (const float*)d_in[3];
    const float* lin_b = (const float*)d_in[4];
    const float* M     = (const float*)d_in[5];
    float*  h     = (float*)d_out;        // N*D fp32, ping
    __half* table = (__half*)d_ws;        // N*D fp16 gather table (7.7 MB)

    k_lin_exp<<<NN / 24, 256, 0, stream>>>(x, lin_W, lin_b, h);
    // layer 0
    k_msg_aux<<<NN / 24, 256, 0, stream>>>(h, M, table);
    k_layer<<<NN / 4, 256, 0, stream>>>(table, adj, w, h);
    // layer 1
    k_msg_aux<<<NN / 24, 256, 0, stream>>>(h, M, table);
    k_layer<<<NN / 4, 256, 0, stream>>>(table, adj, w, h);
}